// Round 15
// baseline (24.050 us; speedup 1.0000x reference)
//
#include <hip/hip_runtime.h>
#include <math.h>

#define N_HI 192      // IMAGE_RES_OUT * IMAGE_UPSCALE
#define NOUT 96
#define FOUT 32
#define MAXPG 392     // 2 cols x 192 records max + 4 pads + align slack

typedef float f2 __attribute__((ext_vector_type(2)));

__device__ __forceinline__ float fast_exp2(float x) {
#if __has_builtin(__builtin_amdgcn_exp2f)
    return __builtin_amdgcn_exp2f(x);
#else
    return exp2f(x);
#endif
}
__device__ __forceinline__ float fast_rcp(float x) {
#if __has_builtin(__builtin_amdgcn_rcpf)
    return __builtin_amdgcn_rcpf(x);
#else
    return 1.0f / x;
#endif
}
__device__ __forceinline__ int lane_rank(unsigned long long m) {
    return (int)__builtin_amdgcn_mbcnt_hi((unsigned)(m >> 32),
            __builtin_amdgcn_mbcnt_lo((unsigned)m, 0u));
}

__global__ __launch_bounds__(256) void cube_sim_kernel(
    const float* __restrict__ p_inc, const float* __restrict__ p_rot,
    const float* __restrict__ p_lb,  const float* __restrict__ p_vs,
    const float* __restrict__ p_vmax,const float* __restrict__ p_rc,
    const float* __restrict__ p_Rd,  const float* __restrict__ p_hz,
    const float* __restrict__ freqs, float* __restrict__ out)
{
    const int tid  = threadIdx.x;
    const int w    = tid >> 6;        // wave id = output pixel within 2x2 tile
    const int lane = tid & 63;
    const int half = lane >> 5;       // record-pair parity this lane serves
    const int l32  = lane & 31;       // output channel this lane owns

    const int jo2 = 2 * blockIdx.x + (w & 1);   // output pixel coords
    const int io2 = 2 * blockIdx.y + (w >> 1);

    __shared__ alignas(16) float qo_s[4][MAXPG];  // SoA record streams (wave-private)
    __shared__ alignas(16) float nL_s[4][MAXPG];

    // ---- uniform scalar setup (once per wave, amortized over 4 columns) ----
    const float FOV    = 500.0f;
    const float C_KMS  = 299792.458f;
    const float F_REST = 230.538f;
    const float LOG2E  = 1.4426950408889634f;
    const float LN2    = 0.6931471805599453f;

    const float inc    = *p_inc;
    const float rot    = *p_rot;
    const float lb     = *p_lb;
    const float vshift = *p_vs;
    const float vmax   = *p_vmax;
    const float rc     = *p_rc;
    const float Rd     = *p_Rd;
    const float hz     = *p_hz;
    const float f0     = freqs[0];
    const float f_last = freqs[FOUT - 1];

    const float cr = __cosf(rot), sr = __sinf(rot);
    const float ci = __cosf(inc), si = __sinf(inc);

    const float dx     = 2.0f * FOV / (float)(N_HI - 1);
    const float Rmin   = 0.1f * (2.0f * FOV / (float)N_HI);
    const float rc2pm  = rc * rc + Rmin * Rmin;
    const float sig_sq = lb * lb;
    const float pc2    = (0.5f * fast_rcp(sig_sq)) * LOG2E;
    const float kR     = LOG2E * fast_rcp(Rd);
    const float kz     = 0.5f * LOG2E * fast_rcp(hz * hz);
    const float THR_P  = 13.2877f;        // -log2(1e-4) survivor cutoff

    const float fstep = (f_last - f0) * (1.0f / 127.0f);
    const float vlA   = C_KMS * (1.0f - f0 * (1.0f / F_REST)) - vshift;
    const float vlB   = -C_KMS * fstep * (1.0f / F_REST);   // km/s per subchannel
    const float invB  = fast_rcp(vlB);
    const float cA    = -vlA * invB;                        // fc (subch units)
    const float cgp   = pc2 * vlB * vlB;
    const float s     = sqrtf(cgp);

    // box-average moment match (sigma_e^2 = sigma^2 + 1.25 subch^2)
    const bool  use_box = (cgp <= 0.22f);
    const float cgp_e = cgp * fast_rcp(1.0f + 2.5f * LN2 * cgp);
    const float s_e   = sqrtf(cgp_e);
    const float dL    = 0.5f * __log2f(1.0f + 2.5f * LN2 * cgp);

    const float sSel = use_box ? s_e : s;
    const float qoff = use_box ? 1.5f : 0.0f;
    const float dLs  = use_box ? dL : 0.0f;
    const float sq   = sSel * qoff;

    // z-band uniforms (exact: alive => |rz| <= Bz); niter=2 needs klo0 <= 64
    const float Bz    = hz * sqrtf(2.0f * THR_P / LOG2E);
    const float rci   = fast_rcp(ci);
    const float rdx   = fast_rcp(dx);
    const float spanu = fabsf(2.0f * Bz * rci) * rdx;
    const bool  band2 = (spanu <= 124.0f);

    const float w4 = (4.0f * sSel) * (float)l32;   // lane's channel coordinate
    const f2    w42 = { w4, w4 };

    f2 acc2 = { 0.0f, 0.0f };                      // carried across all columns

    // ============ two groups of 2 columns; merged SoA record stream each ====
    #pragma unroll
    for (int grp = 0; grp < 2; ++grp) {
        // ---- phase 1: append 2 columns' records into the streams ----
        int cnt = 0;
        #pragma unroll
        for (int cc = 0; cc < 2; ++cc) {
            const int c4 = 2 * grp + cc;
            const int i = 2 * io2 + (c4 >> 1);
            const int j = 2 * jo2 + (c4 & 1);
            const float x  = __builtin_fmaf(dx, (float)i, -FOV);
            const float y  = __builtin_fmaf(dx, (float)j, -FOV);
            const float rx = cr * x - sr * y;
            const float y1 = sr * x + cr * y;
            const float ciy1 = ci * y1, siy1 = si * y1;
            const float nsvrx = -si * vmax * rx;
            const float rx2   = rx * rx;
            const float rx2c  = rx2 + rc2pm;

            int niter = 3, klo0 = 0;
            if (band2) {
                const float zlo = fminf((-Bz - siy1) * rci, (Bz - siy1) * rci);
                const int kl = (int)floorf((zlo + FOV) * rdx) - 1;
                klo0 = min(max(kl, 0), 64);   // kv <= 191: no phantom voxels
                niter = 2;
            }

            for (int c = 0; c < niter; ++c) {
                const int kv = klo0 + c * 64 + lane;
                const float z  = __builtin_fmaf(dx, (float)kv, -FOV);
                const float ry = __builtin_fmaf(-si, z, ciy1);
                const float rz = __builtin_fmaf( ci, z, siy1);
                const float ry2 = ry * ry;
                const float R  = sqrtf(__builtin_fmaf(ry, ry, rx2));
                const float nL = __builtin_fmaf(R, kR, rz * rz * kz);
                const float inv  = __frsqrt_rn(ry2 + rx2c);
                const float vlos = nsvrx * inv;
                const float fc   = __builtin_fmaf(vlos, invB, cA);
                const bool alive = (nL <= THR_P);
                const unsigned long long m = __ballot(alive);
                if (alive) {
                    const int pos = cnt + lane_rank(m);
                    qo_s[w][pos] = __builtin_fmaf(-fc, sSel, sq);  // sSel*(qoff-fc)
                    nL_s[w][pos] = nL + dLs;
                }
                cnt += (int)__popcll(m);
            }
        }
        if (lane < 4) {   // 4 dead pads: exp2(-(d^2+1e5)) -> 0
            qo_s[w][cnt + lane] = 0.0f;
            nL_s[w][cnt + lane] = 100000.0f;
        }

        // ---- phase 2: 4 records/iter; half h serves records 4it+2h, 4it+2h+1 ----
        const int nIter = (cnt + 3) >> 2;
        const float* qp = &qo_s[w][2 * half];
        const float* lp = &nL_s[w][2 * half];
        if (use_box) {
            for (int it = 0; it < nIter; ++it) {
                const f2 qo2 = *reinterpret_cast<const f2*>(qp + 4 * it); // ds_read_b64
                const f2 nl2 = *reinterpret_cast<const f2*>(lp + 4 * it); // (2-way bcast)
                const f2 d2  = w42 + qo2;                          // v_pk_add_f32
                const f2 e2  = __builtin_elementwise_fma(d2, d2, nl2); // v_pk_fma_f32
                f2 r2;
                r2.x = fast_exp2(-e2.x);
                r2.y = fast_exp2(-e2.y);
                acc2 = acc2 + r2;                                  // v_pk_add_f32
            }
        } else {
            // exact 4-subchannel fallback (narrow line widths only)
            for (int it = 0; it < nIter; ++it) {
                #pragma unroll
                for (int rr = 0; rr < 2; ++rr) {
                    const float qo = qp[4 * it + rr];
                    const float nl = lp[4 * it + rr];
                    const float db = w4 + qo;
                    #pragma unroll
                    for (int fu = 0; fu < 4; ++fu) {
                        const float d = __builtin_fmaf((float)fu, sSel, db);
                        acc2.x += fast_exp2(-__builtin_fmaf(d, d, nl));
                    }
                }
            }
        }
    }

    // ---- final: fold halves across lane^32, store 32 channels ----
    float asum = acc2.x + acc2.y;
    asum += __shfl_xor(asum, 32, 64);
    if (lane < FOUT) {
        const float normc = __frsqrt_rn(2.0f * 3.14159265358979f * sig_sq)
                          * (use_box ? 0.25f : 0.0625f);
        out[lane * (NOUT * NOUT) + io2 * NOUT + jo2] = asum * normc;
    }
}

extern "C" void kernel_launch(void* const* d_in, const int* in_sizes, int n_in,
                              void* d_out, int out_size, void* d_ws, size_t ws_size,
                              hipStream_t stream) {
    const float* p_inc  = (const float*)d_in[0];
    const float* p_rot  = (const float*)d_in[1];
    const float* p_lb   = (const float*)d_in[2];
    const float* p_vs   = (const float*)d_in[3];
    const float* p_vmax = (const float*)d_in[4];
    const float* p_rc   = (const float*)d_in[5];
    const float* p_Rd   = (const float*)d_in[6];
    const float* p_hz   = (const float*)d_in[7];
    const float* freqs  = (const float*)d_in[8];
    float* out = (float*)d_out;

    dim3 grid(NOUT / 2, NOUT / 2);
    dim3 block(256);
    cube_sim_kernel<<<grid, block, 0, stream>>>(p_inc, p_rot, p_lb, p_vs,
                                                p_vmax, p_rc, p_Rd, p_hz,
                                                freqs, out);
}

// Round 16
// 22.550 us; speedup vs baseline: 1.0665x; 1.0665x over previous
//
#include <hip/hip_runtime.h>
#include <math.h>

#define N_HI 192      // IMAGE_RES_OUT * IMAGE_UPSCALE
#define NOUT 96
#define FOUT 32
#define NPIX (NOUT * NOUT)       // 9216 output pixels
#define NWAVES 8192              // 2048 blocks x 4 waves: exactly 8 blocks/CU resident
#define MAXPG 392                // 2 cols x 192 records max + 4 pads + align slack

typedef float f2 __attribute__((ext_vector_type(2)));

__device__ __forceinline__ float fast_exp2(float x) {
#if __has_builtin(__builtin_amdgcn_exp2f)
    return __builtin_amdgcn_exp2f(x);
#else
    return exp2f(x);
#endif
}
__device__ __forceinline__ float fast_rcp(float x) {
#if __has_builtin(__builtin_amdgcn_rcpf)
    return __builtin_amdgcn_rcpf(x);
#else
    return 1.0f / x;
#endif
}
__device__ __forceinline__ int lane_rank(unsigned long long m) {
    return (int)__builtin_amdgcn_mbcnt_hi((unsigned)(m >> 32),
            __builtin_amdgcn_mbcnt_lo((unsigned)m, 0u));
}

__global__ __launch_bounds__(256) void cube_sim_kernel(
    const float* __restrict__ p_inc, const float* __restrict__ p_rot,
    const float* __restrict__ p_lb,  const float* __restrict__ p_vs,
    const float* __restrict__ p_vmax,const float* __restrict__ p_rc,
    const float* __restrict__ p_Rd,  const float* __restrict__ p_hz,
    const float* __restrict__ freqs, float* __restrict__ out)
{
    const int tid  = threadIdx.x;
    const int w    = tid >> 6;        // wave id within block
    const int lane = tid & 63;
    const int half = lane >> 5;       // record-pair parity this lane serves
    const int l32  = lane & 31;       // output channel this lane owns
    const int wgid = blockIdx.x * 4 + w;   // global wave id in [0, NWAVES)

    __shared__ alignas(16) float qo_s[4][MAXPG];  // SoA record streams (wave-private)
    __shared__ alignas(16) float nL_s[4][MAXPG];

    // ---- uniform scalar setup (once per wave, amortized over all pixels) ----
    const float FOV    = 500.0f;
    const float C_KMS  = 299792.458f;
    const float F_REST = 230.538f;
    const float LOG2E  = 1.4426950408889634f;
    const float LN2    = 0.6931471805599453f;

    const float inc    = *p_inc;
    const float rot    = *p_rot;
    const float lb     = *p_lb;
    const float vshift = *p_vs;
    const float vmax   = *p_vmax;
    const float rc     = *p_rc;
    const float Rd     = *p_Rd;
    const float hz     = *p_hz;
    const float f0     = freqs[0];
    const float f_last = freqs[FOUT - 1];

    const float cr = __cosf(rot), sr = __sinf(rot);
    const float ci = __cosf(inc), si = __sinf(inc);

    const float dx     = 2.0f * FOV / (float)(N_HI - 1);
    const float Rmin   = 0.1f * (2.0f * FOV / (float)N_HI);
    const float rc2pm  = rc * rc + Rmin * Rmin;
    const float sig_sq = lb * lb;
    const float pc2    = (0.5f * fast_rcp(sig_sq)) * LOG2E;
    const float kR     = LOG2E * fast_rcp(Rd);
    const float kz     = 0.5f * LOG2E * fast_rcp(hz * hz);
    const float THR_P  = 13.2877f;        // -log2(1e-4) survivor cutoff

    const float fstep = (f_last - f0) * (1.0f / 127.0f);
    const float vlA   = C_KMS * (1.0f - f0 * (1.0f / F_REST)) - vshift;
    const float vlB   = -C_KMS * fstep * (1.0f / F_REST);   // km/s per subchannel
    const float invB  = fast_rcp(vlB);
    const float cA    = -vlA * invB;                        // fc (subch units)
    const float cgp   = pc2 * vlB * vlB;
    const float s     = sqrtf(cgp);

    // box-average moment match (sigma_e^2 = sigma^2 + 1.25 subch^2)
    const bool  use_box = (cgp <= 0.22f);
    const float cgp_e = cgp * fast_rcp(1.0f + 2.5f * LN2 * cgp);
    const float s_e   = sqrtf(cgp_e);
    const float dL    = 0.5f * __log2f(1.0f + 2.5f * LN2 * cgp);

    const float sSel = use_box ? s_e : s;
    const float qoff = use_box ? 1.5f : 0.0f;
    const float dLs  = use_box ? dL : 0.0f;
    const float sq   = sSel * qoff;

    // z-band uniforms (exact: alive => |rz| <= Bz); niter=2 needs klo0 <= 64
    const float Bz    = hz * sqrtf(2.0f * THR_P / LOG2E);
    const float rci   = fast_rcp(ci);
    const float rdx   = fast_rcp(dx);
    const float spanu = fabsf(2.0f * Bz * rci) * rdx;
    const bool  band2 = (spanu <= 124.0f);

    const float w4 = (4.0f * sSel) * (float)l32;   // lane's channel coordinate
    const f2    w42 = { w4, w4 };
    const float normc = __frsqrt_rn(2.0f * 3.14159265358979f * sig_sq)
                      * (use_box ? 0.25f : 0.0625f);

    // ============ grid-stride over output pixels (1-2 pixels per wave) ======
    for (int p = wgid; p < NPIX; p += NWAVES) {
        const int io2 = (int)(((unsigned)p * 43691u) >> 22);   // p / 96 (exact, p<9216)
        const int jo2 = p - io2 * NOUT;

        f2 acc2 = { 0.0f, 0.0f };

        #pragma unroll
        for (int grp = 0; grp < 2; ++grp) {
            // ---- phase 1: append 2 columns' records into the streams ----
            int cnt = 0;
            #pragma unroll
            for (int cc = 0; cc < 2; ++cc) {
                const int c4 = 2 * grp + cc;
                const int i = 2 * io2 + (c4 >> 1);
                const int j = 2 * jo2 + (c4 & 1);
                const float x  = __builtin_fmaf(dx, (float)i, -FOV);
                const float y  = __builtin_fmaf(dx, (float)j, -FOV);
                const float rx = cr * x - sr * y;
                const float y1 = sr * x + cr * y;
                const float ciy1 = ci * y1, siy1 = si * y1;
                const float nsvrx = -si * vmax * rx;
                const float rx2   = rx * rx;
                const float rx2c  = rx2 + rc2pm;

                int niter = 3, klo0 = 0;
                if (band2) {
                    const float zlo = fminf((-Bz - siy1) * rci, (Bz - siy1) * rci);
                    const int kl = (int)floorf((zlo + FOV) * rdx) - 1;
                    klo0 = min(max(kl, 0), 64);   // kv <= 191: no phantom voxels
                    niter = 2;
                }

                for (int c = 0; c < niter; ++c) {
                    const int kv = klo0 + c * 64 + lane;
                    const float z  = __builtin_fmaf(dx, (float)kv, -FOV);
                    const float ry = __builtin_fmaf(-si, z, ciy1);
                    const float rz = __builtin_fmaf( ci, z, siy1);
                    const float ry2 = ry * ry;
                    const float R  = sqrtf(__builtin_fmaf(ry, ry, rx2));
                    const float nL = __builtin_fmaf(R, kR, rz * rz * kz);
                    const float inv  = __frsqrt_rn(ry2 + rx2c);
                    const float vlos = nsvrx * inv;
                    const float fc   = __builtin_fmaf(vlos, invB, cA);
                    const bool alive = (nL <= THR_P);
                    const unsigned long long m = __ballot(alive);
                    if (alive) {
                        const int pos = cnt + lane_rank(m);
                        qo_s[w][pos] = __builtin_fmaf(-fc, sSel, sq);  // sSel*(qoff-fc)
                        nL_s[w][pos] = nL + dLs;
                    }
                    cnt += (int)__popcll(m);
                }
            }
            if (lane < 4) {   // 4 dead pads: exp2(-(d^2+1e5)) -> 0
                qo_s[w][cnt + lane] = 0.0f;
                nL_s[w][cnt + lane] = 100000.0f;
            }

            // ---- phase 2: 4 records/iter; half h serves records 4it+2h, +1 ----
            const int nIter = (cnt + 3) >> 2;
            const float* qp = &qo_s[w][2 * half];
            const float* lp = &nL_s[w][2 * half];
            if (use_box) {
                for (int it = 0; it < nIter; ++it) {
                    const f2 qo2 = *reinterpret_cast<const f2*>(qp + 4 * it);
                    const f2 nl2 = *reinterpret_cast<const f2*>(lp + 4 * it);
                    const f2 d2  = w42 + qo2;
                    const f2 e2  = __builtin_elementwise_fma(d2, d2, nl2);
                    f2 r2;
                    r2.x = fast_exp2(-e2.x);
                    r2.y = fast_exp2(-e2.y);
                    acc2 = acc2 + r2;
                }
            } else {
                // exact 4-subchannel fallback (narrow line widths only)
                for (int it = 0; it < nIter; ++it) {
                    #pragma unroll
                    for (int rr = 0; rr < 2; ++rr) {
                        const float qo = qp[4 * it + rr];
                        const float nl = lp[4 * it + rr];
                        const float db = w4 + qo;
                        #pragma unroll
                        for (int fu = 0; fu < 4; ++fu) {
                            const float d = __builtin_fmaf((float)fu, sSel, db);
                            acc2.x += fast_exp2(-__builtin_fmaf(d, d, nl));
                        }
                    }
                }
            }
        }

        // ---- fold halves across lane^32, store this pixel's 32 channels ----
        float asum = acc2.x + acc2.y;
        asum += __shfl_xor(asum, 32, 64);
        if (lane < FOUT)
            out[lane * NPIX + p] = asum * normc;
    }
}

extern "C" void kernel_launch(void* const* d_in, const int* in_sizes, int n_in,
                              void* d_out, int out_size, void* d_ws, size_t ws_size,
                              hipStream_t stream) {
    const float* p_inc  = (const float*)d_in[0];
    const float* p_rot  = (const float*)d_in[1];
    const float* p_lb   = (const float*)d_in[2];
    const float* p_vs   = (const float*)d_in[3];
    const float* p_vmax = (const float*)d_in[4];
    const float* p_rc   = (const float*)d_in[5];
    const float* p_Rd   = (const float*)d_in[6];
    const float* p_hz   = (const float*)d_in[7];
    const float* freqs  = (const float*)d_in[8];
    float* out = (float*)d_out;

    dim3 grid(NWAVES / 4);
    dim3 block(256);
    cube_sim_kernel<<<grid, block, 0, stream>>>(p_inc, p_rot, p_lb, p_vs,
                                                p_vmax, p_rc, p_Rd, p_hz,
                                                freqs, out);
}

// Round 17
// 21.612 us; speedup vs baseline: 1.1128x; 1.0434x over previous
//
#include <hip/hip_runtime.h>
#include <math.h>

#define N_HI 192      // IMAGE_RES_OUT * IMAGE_UPSCALE
#define NOUT 96
#define FOUT 32
#define NPIX (NOUT * NOUT)       // 9216 output pixels
#define NWAVES 8192              // 2048 blocks x 4 waves: 8 blocks/CU all resident
#define MAXPG 392                // 2 cols x 192 records max + 4 pads + align slack

typedef float f2 __attribute__((ext_vector_type(2)));

__device__ __forceinline__ float fast_exp2(float x) {
#if __has_builtin(__builtin_amdgcn_exp2f)
    return __builtin_amdgcn_exp2f(x);
#else
    return exp2f(x);
#endif
}
__device__ __forceinline__ float fast_rcp(float x) {
#if __has_builtin(__builtin_amdgcn_rcpf)
    return __builtin_amdgcn_rcpf(x);
#else
    return 1.0f / x;
#endif
}
__device__ __forceinline__ int lane_rank(unsigned long long m) {
    return (int)__builtin_amdgcn_mbcnt_hi((unsigned)(m >> 32),
            __builtin_amdgcn_mbcnt_lo((unsigned)m, 0u));
}

__global__ __launch_bounds__(256) void cube_sim_kernel(
    const float* __restrict__ p_inc, const float* __restrict__ p_rot,
    const float* __restrict__ p_lb,  const float* __restrict__ p_vs,
    const float* __restrict__ p_vmax,const float* __restrict__ p_rc,
    const float* __restrict__ p_Rd,  const float* __restrict__ p_hz,
    const float* __restrict__ freqs, float* __restrict__ out)
{
    const int tid  = threadIdx.x;
    const int w    = tid >> 6;        // wave id within block
    const int lane = tid & 63;
    const int half = lane >> 5;       // record-pair parity this lane serves
    const int l32  = lane & 31;       // output channel this lane owns
    const int wgid = blockIdx.x * 4 + w;   // global wave id in [0, NWAVES)

    __shared__ alignas(16) float qo_s[4][MAXPG];  // SoA record streams (wave-private)
    __shared__ alignas(16) float nL_s[4][MAXPG];
    __shared__ float comb[4][FOUT];               // split-pixel partial sums

    // ---- uniform scalar setup (once per wave) ----
    const float FOV    = 500.0f;
    const float C_KMS  = 299792.458f;
    const float F_REST = 230.538f;
    const float LOG2E  = 1.4426950408889634f;
    const float LN2    = 0.6931471805599453f;

    const float inc    = *p_inc;
    const float rot    = *p_rot;
    const float lb     = *p_lb;
    const float vshift = *p_vs;
    const float vmax   = *p_vmax;
    const float rc     = *p_rc;
    const float Rd     = *p_Rd;
    const float hz     = *p_hz;
    const float f0     = freqs[0];
    const float f_last = freqs[FOUT - 1];

    const float cr = __cosf(rot), sr = __sinf(rot);
    const float ci = __cosf(inc), si = __sinf(inc);

    const float dx     = 2.0f * FOV / (float)(N_HI - 1);
    const float Rmin   = 0.1f * (2.0f * FOV / (float)N_HI);
    const float rc2pm  = rc * rc + Rmin * Rmin;
    const float sig_sq = lb * lb;
    const float pc2    = (0.5f * fast_rcp(sig_sq)) * LOG2E;
    const float kR     = LOG2E * fast_rcp(Rd);
    const float kz     = 0.5f * LOG2E * fast_rcp(hz * hz);
    const float THR_P  = 11.2877f;        // -log2(4e-4) survivor cutoff

    const float fstep = (f_last - f0) * (1.0f / 127.0f);
    const float vlA   = C_KMS * (1.0f - f0 * (1.0f / F_REST)) - vshift;
    const float vlB   = -C_KMS * fstep * (1.0f / F_REST);   // km/s per subchannel
    const float invB  = fast_rcp(vlB);
    const float cA    = -vlA * invB;                        // fc (subch units)
    const float cgp   = pc2 * vlB * vlB;
    const float s     = sqrtf(cgp);

    // box-average moment match (sigma_e^2 = sigma^2 + 1.25 subch^2)
    const bool  use_box = (cgp <= 0.22f);
    const float cgp_e = cgp * fast_rcp(1.0f + 2.5f * LN2 * cgp);
    const float s_e   = sqrtf(cgp_e);
    const float dL    = 0.5f * __log2f(1.0f + 2.5f * LN2 * cgp);

    const float sSel = use_box ? s_e : s;
    const float qoff = use_box ? 1.5f : 0.0f;
    const float dLs  = use_box ? dL : 0.0f;
    const float sq   = sSel * qoff;

    // z-band uniforms (exact: alive => |rz| <= Bz); niter=2 needs klo0 <= 64
    const float Bz    = hz * sqrtf(2.0f * THR_P / LOG2E);
    const float rci   = fast_rcp(ci);
    const float rdx   = fast_rcp(dx);
    const float spanu = fabsf(2.0f * Bz * rci) * rdx;
    const bool  band2 = (spanu <= 124.0f);

    const float w4 = (4.0f * sSel) * (float)l32;   // lane's channel coordinate
    const f2    w42 = { w4, w4 };
    const float normc = __frsqrt_rn(2.0f * 3.14159265358979f * sig_sq)
                      * (use_box ? 0.25f : 0.0625f);

    // ---- per-pixel worker: accumulate column groups [g0, g1) of pixel p ----
    auto do_groups = [&](int p, int g0, int g1) -> float {
        const int io2 = (int)(((unsigned)p * 43691u) >> 22);   // p / 96 (exact)
        const int jo2 = p - io2 * NOUT;
        f2 acc2 = { 0.0f, 0.0f };
        for (int grp = g0; grp < g1; ++grp) {
            // phase 1: append 2 columns' records into the streams
            int cnt = 0;
            #pragma unroll
            for (int cc = 0; cc < 2; ++cc) {
                const int c4 = 2 * grp + cc;
                const int i = 2 * io2 + (c4 >> 1);
                const int j = 2 * jo2 + (c4 & 1);
                const float x  = __builtin_fmaf(dx, (float)i, -FOV);
                const float y  = __builtin_fmaf(dx, (float)j, -FOV);
                const float rx = cr * x - sr * y;
                const float y1 = sr * x + cr * y;
                const float ciy1 = ci * y1, siy1 = si * y1;
                const float nsvrx = -si * vmax * rx;
                const float rx2   = rx * rx;
                const float rx2c  = rx2 + rc2pm;

                int niter = 3, klo0 = 0;
                if (band2) {
                    const float zlo = fminf((-Bz - siy1) * rci, (Bz - siy1) * rci);
                    const int kl = (int)floorf((zlo + FOV) * rdx) - 1;
                    klo0 = min(max(kl, 0), 64);   // kv <= 191: no phantom voxels
                    niter = 2;
                }
                for (int c = 0; c < niter; ++c) {
                    const int kv = klo0 + c * 64 + lane;
                    const float z  = __builtin_fmaf(dx, (float)kv, -FOV);
                    const float ry = __builtin_fmaf(-si, z, ciy1);
                    const float rz = __builtin_fmaf( ci, z, siy1);
                    const float ry2 = ry * ry;
                    const float R  = sqrtf(__builtin_fmaf(ry, ry, rx2));
                    const float nL = __builtin_fmaf(R, kR, rz * rz * kz);
                    const float inv  = __frsqrt_rn(ry2 + rx2c);
                    const float vlos = nsvrx * inv;
                    const float fc   = __builtin_fmaf(vlos, invB, cA);
                    const bool alive = (nL <= THR_P);
                    const unsigned long long m = __ballot(alive);
                    if (alive) {
                        const int pos = cnt + lane_rank(m);
                        qo_s[w][pos] = __builtin_fmaf(-fc, sSel, sq);
                        nL_s[w][pos] = nL + dLs;
                    }
                    cnt += (int)__popcll(m);
                }
            }
            if (lane < 4) {   // dead pads: exp2(-(d^2+1e5)) -> 0
                qo_s[w][cnt + lane] = 0.0f;
                nL_s[w][cnt + lane] = 100000.0f;
            }
            // phase 2: 4 records/iter; half h serves records 4it+2h, 4it+2h+1
            const int nIter = (cnt + 3) >> 2;
            const float* qp = &qo_s[w][2 * half];
            const float* lp = &nL_s[w][2 * half];
            if (use_box) {
                for (int it = 0; it < nIter; ++it) {
                    const f2 qo2 = *reinterpret_cast<const f2*>(qp + 4 * it);
                    const f2 nl2 = *reinterpret_cast<const f2*>(lp + 4 * it);
                    const f2 d2  = w42 + qo2;
                    const f2 e2  = __builtin_elementwise_fma(d2, d2, nl2);
                    f2 r2;
                    r2.x = fast_exp2(-e2.x);
                    r2.y = fast_exp2(-e2.y);
                    acc2 = acc2 + r2;
                }
            } else {
                for (int it = 0; it < nIter; ++it) {
                    #pragma unroll
                    for (int rr = 0; rr < 2; ++rr) {
                        const float qo = qp[4 * it + rr];
                        const float nl = lp[4 * it + rr];
                        const float db = w4 + qo;
                        #pragma unroll
                        for (int fu = 0; fu < 4; ++fu) {
                            const float d = __builtin_fmaf((float)fu, sSel, db);
                            acc2.x += fast_exp2(-__builtin_fmaf(d, d, nl));
                        }
                    }
                }
            }
        }
        float asum = acc2.x + acc2.y;
        asum += __shfl_xor(asum, 32, 64);        // fold record-parity halves
        return asum;
    };

    // ---- main pixel: one full pixel per wave ----
    {
        const float asum = do_groups(wgid, 0, 2);
        if (lane < FOUT) {
            const int p = wgid;
            out[lane * NPIX + p] = asum * normc;
        }
    }

    // ---- remainder pixels 8192..9215: split across wave pairs (2u, 2u+1) ----
    float asum2 = 0.0f;
    int p2 = 0;
    const bool has_extra = (wgid < 2 * (NPIX - NWAVES));      // wgid < 2048
    if (has_extra) {
        p2 = NWAVES + (wgid >> 1);
        asum2 = do_groups(p2, w & 1, (w & 1) + 1);            // 2 columns each
        if ((w & 1) == 1 && lane < FOUT) comb[w][lane] = asum2;
    }
    if (blockIdx.x < 512) __syncthreads();                    // uniform per block
    if (has_extra && (w & 1) == 0 && lane < FOUT)
        out[lane * NPIX + p2] = (asum2 + comb[w + 1][lane]) * normc;
}

extern "C" void kernel_launch(void* const* d_in, const int* in_sizes, int n_in,
                              void* d_out, int out_size, void* d_ws, size_t ws_size,
                              hipStream_t stream) {
    const float* p_inc  = (const float*)d_in[0];
    const float* p_rot  = (const float*)d_in[1];
    const float* p_lb   = (const float*)d_in[2];
    const float* p_vs   = (const float*)d_in[3];
    const float* p_vmax = (const float*)d_in[4];
    const float* p_rc   = (const float*)d_in[5];
    const float* p_Rd   = (const float*)d_in[6];
    const float* p_hz   = (const float*)d_in[7];
    const float* freqs  = (const float*)d_in[8];
    float* out = (float*)d_out;

    dim3 grid(NWAVES / 4);
    dim3 block(256);
    cube_sim_kernel<<<grid, block, 0, stream>>>(p_inc, p_rot, p_lb, p_vs,
                                                p_vmax, p_rc, p_Rd, p_hz,
                                                freqs, out);
}

// Round 18
// 21.059 us; speedup vs baseline: 1.1420x; 1.0262x over previous
//
#include <hip/hip_runtime.h>
#include <math.h>

#define N_HI 192      // IMAGE_RES_OUT * IMAGE_UPSCALE
#define NOUT 96
#define FOUT 32
#define NPIX (NOUT * NOUT)       // 9216 output pixels
#define NWAVES 8192              // 2048 blocks x 4 waves: 8 blocks/CU all resident
#define MAXPG 392                // 2 cols x 192 records max + 4 pads + align slack

typedef float f2 __attribute__((ext_vector_type(2)));

__device__ __forceinline__ float fast_exp2(float x) {
#if __has_builtin(__builtin_amdgcn_exp2f)
    return __builtin_amdgcn_exp2f(x);
#else
    return exp2f(x);
#endif
}
__device__ __forceinline__ float fast_rcp(float x) {
#if __has_builtin(__builtin_amdgcn_rcpf)
    return __builtin_amdgcn_rcpf(x);
#else
    return 1.0f / x;
#endif
}
__device__ __forceinline__ int lane_rank(unsigned long long m) {
    return (int)__builtin_amdgcn_mbcnt_hi((unsigned)(m >> 32),
            __builtin_amdgcn_mbcnt_lo((unsigned)m, 0u));
}

__global__ __launch_bounds__(256, 8) void cube_sim_kernel(
    const float* __restrict__ p_inc, const float* __restrict__ p_rot,
    const float* __restrict__ p_lb,  const float* __restrict__ p_vs,
    const float* __restrict__ p_vmax,const float* __restrict__ p_rc,
    const float* __restrict__ p_Rd,  const float* __restrict__ p_hz,
    const float* __restrict__ freqs, float* __restrict__ out)
{
    const int tid  = threadIdx.x;
    const int w    = tid >> 6;        // wave id within block
    const int lane = tid & 63;
    const int half = lane >> 5;       // record-pair parity this lane serves
    const int l32  = lane & 31;       // output channel this lane owns
    const int wgid = blockIdx.x * 4 + w;   // global wave id in [0, NWAVES)

    __shared__ alignas(16) float qo_s[4][MAXPG];  // SoA record streams (wave-private)
    __shared__ alignas(16) float nL_s[4][MAXPG];
    __shared__ float comb[4][FOUT];               // split-pixel partial sums

    // ---- uniform scalar setup (once per wave) ----
    const float FOV    = 500.0f;
    const float C_KMS  = 299792.458f;
    const float F_REST = 230.538f;
    const float LOG2E  = 1.4426950408889634f;
    const float LN2    = 0.6931471805599453f;

    const float inc    = *p_inc;
    const float rot    = *p_rot;
    const float lb     = *p_lb;
    const float vshift = *p_vs;
    const float vmax   = *p_vmax;
    const float rc     = *p_rc;
    const float Rd     = *p_Rd;
    const float hz     = *p_hz;
    const float f0     = freqs[0];
    const float f_last = freqs[FOUT - 1];

    const float cr = __cosf(rot), sr = __sinf(rot);
    const float ci = __cosf(inc), si = __sinf(inc);

    const float dx     = 2.0f * FOV / (float)(N_HI - 1);
    const float Rmin   = 0.1f * (2.0f * FOV / (float)N_HI);
    const float rc2pm  = rc * rc + Rmin * Rmin;
    const float sig_sq = lb * lb;
    const float pc2    = (0.5f * fast_rcp(sig_sq)) * LOG2E;
    const float kR     = LOG2E * fast_rcp(Rd);
    const float kz     = 0.5f * LOG2E * fast_rcp(hz * hz);
    const float THR_P  = 11.2877f;        // -log2(4e-4) survivor cutoff

    const float fstep = (f_last - f0) * (1.0f / 127.0f);
    const float vlA   = C_KMS * (1.0f - f0 * (1.0f / F_REST)) - vshift;
    const float vlB   = -C_KMS * fstep * (1.0f / F_REST);   // km/s per subchannel
    const float invB  = fast_rcp(vlB);
    const float cA    = -vlA * invB;                        // fc (subch units)
    const float cgp   = pc2 * vlB * vlB;
    const float s     = sqrtf(cgp);

    // box-average moment match (sigma_e^2 = sigma^2 + 1.25 subch^2)
    const bool  use_box = (cgp <= 0.22f);
    const float cgp_e = cgp * fast_rcp(1.0f + 2.5f * LN2 * cgp);
    const float s_e   = sqrtf(cgp_e);
    const float dL    = 0.5f * __log2f(1.0f + 2.5f * LN2 * cgp);

    const float sSel = use_box ? s_e : s;
    const float qoff = use_box ? 1.5f : 0.0f;
    const float dLs  = use_box ? dL : 0.0f;
    const float sq   = sSel * qoff;

    // z-band uniforms (exact: alive => |rz| <= Bz); niter=2 needs klo0 <= 64
    const float Bz    = hz * sqrtf(2.0f * THR_P / LOG2E);
    const float rci   = fast_rcp(ci);
    const float rdx   = fast_rcp(dx);
    const float spanu = fabsf(2.0f * Bz * rci) * rdx;
    const bool  band2 = (spanu <= 124.0f);

    const float w4 = (4.0f * sSel) * (float)l32;   // lane's channel coordinate
    const f2    w42 = { w4, w4 };
    const float normc = __frsqrt_rn(2.0f * 3.14159265358979f * sig_sq)
                      * (use_box ? 0.25f : 0.0625f);

    // ---- per-pixel worker: accumulate column groups [g0, g1) of pixel p ----
    auto do_groups = [&](int p, int g0, int g1) -> float {
        const int io2 = (int)(((unsigned)p * 43691u) >> 22);   // p / 96 (exact)
        const int jo2 = p - io2 * NOUT;
        f2 acc2 = { 0.0f, 0.0f };
        for (int grp = g0; grp < g1; ++grp) {
            // phase 1: append 2 columns' records into the streams
            int cnt = 0;
            #pragma unroll
            for (int cc = 0; cc < 2; ++cc) {
                const int c4 = 2 * grp + cc;
                const int i = 2 * io2 + (c4 >> 1);
                const int j = 2 * jo2 + (c4 & 1);
                const float x  = __builtin_fmaf(dx, (float)i, -FOV);
                const float y  = __builtin_fmaf(dx, (float)j, -FOV);
                const float rx = cr * x - sr * y;
                const float y1 = sr * x + cr * y;
                const float ciy1 = ci * y1, siy1 = si * y1;
                const float nsvrx = -si * vmax * rx;
                const float rx2   = rx * rx;
                const float rx2c  = rx2 + rc2pm;

                int niter = 3, klo0 = 0;
                if (band2) {
                    const float zlo = fminf((-Bz - siy1) * rci, (Bz - siy1) * rci);
                    const int kl = (int)floorf((zlo + FOV) * rdx) - 1;
                    klo0 = min(max(kl, 0), 64);   // kv <= 191: no phantom voxels
                    niter = 2;
                }
                for (int c = 0; c < niter; ++c) {
                    const int kv = klo0 + c * 64 + lane;
                    const float z  = __builtin_fmaf(dx, (float)kv, -FOV);
                    const float ry = __builtin_fmaf(-si, z, ciy1);
                    const float rz = __builtin_fmaf( ci, z, siy1);
                    const float ry2 = ry * ry;
                    const float R  = sqrtf(__builtin_fmaf(ry, ry, rx2));
                    const float nL = __builtin_fmaf(R, kR, rz * rz * kz);
                    const float inv  = __frsqrt_rn(ry2 + rx2c);
                    const float vlos = nsvrx * inv;
                    const float fc   = __builtin_fmaf(vlos, invB, cA);
                    const bool alive = (nL <= THR_P);
                    const unsigned long long m = __ballot(alive);
                    if (alive) {
                        const int pos = cnt + lane_rank(m);
                        qo_s[w][pos] = __builtin_fmaf(-fc, sSel, sq);
                        nL_s[w][pos] = nL + dLs;
                    }
                    cnt += (int)__popcll(m);
                }
            }
            if (lane < 4) {   // dead pads: exp2(-(d^2+1e5)) -> 0
                qo_s[w][cnt + lane] = 0.0f;
                nL_s[w][cnt + lane] = 100000.0f;
            }
            // phase 2: 4 records/iter; half h serves records 4it+2h, 4it+2h+1
            const int nIter = (cnt + 3) >> 2;
            const float* qp = &qo_s[w][2 * half];
            const float* lp = &nL_s[w][2 * half];
            if (use_box) {
                for (int it = 0; it < nIter; ++it) {
                    const f2 qo2 = *reinterpret_cast<const f2*>(qp + 4 * it);
                    const f2 nl2 = *reinterpret_cast<const f2*>(lp + 4 * it);
                    const f2 d2  = w42 + qo2;
                    const f2 e2  = __builtin_elementwise_fma(d2, d2, nl2);
                    f2 r2;
                    r2.x = fast_exp2(-e2.x);
                    r2.y = fast_exp2(-e2.y);
                    acc2 = acc2 + r2;
                }
            } else {
                for (int it = 0; it < nIter; ++it) {
                    #pragma unroll
                    for (int rr = 0; rr < 2; ++rr) {
                        const float qo = qp[4 * it + rr];
                        const float nl = lp[4 * it + rr];
                        const float db = w4 + qo;
                        #pragma unroll
                        for (int fu = 0; fu < 4; ++fu) {
                            const float d = __builtin_fmaf((float)fu, sSel, db);
                            acc2.x += fast_exp2(-__builtin_fmaf(d, d, nl));
                        }
                    }
                }
            }
        }
        float asum = acc2.x + acc2.y;
        asum += __shfl_xor(asum, 32, 64);        // fold record-parity halves
        return asum;
    };

    // ---- main pixel: one full pixel per wave ----
    {
        const float asum = do_groups(wgid, 0, 2);
        if (lane < FOUT) {
            const int p = wgid;
            out[lane * NPIX + p] = asum * normc;
        }
    }

    // ---- remainder pixels 8192..9215: split across wave pairs (2u, 2u+1) ----
    float asum2 = 0.0f;
    int p2 = 0;
    const bool has_extra = (wgid < 2 * (NPIX - NWAVES));      // wgid < 2048
    if (has_extra) {
        p2 = NWAVES + (wgid >> 1);
        asum2 = do_groups(p2, w & 1, (w & 1) + 1);            // 2 columns each
        if ((w & 1) == 1 && lane < FOUT) comb[w][lane] = asum2;
    }
    if (blockIdx.x < 512) __syncthreads();                    // uniform per block
    if (has_extra && (w & 1) == 0 && lane < FOUT)
        out[lane * NPIX + p2] = (asum2 + comb[w + 1][lane]) * normc;
}

extern "C" void kernel_launch(void* const* d_in, const int* in_sizes, int n_in,
                              void* d_out, int out_size, void* d_ws, size_t ws_size,
                              hipStream_t stream) {
    const float* p_inc  = (const float*)d_in[0];
    const float* p_rot  = (const float*)d_in[1];
    const float* p_lb   = (const float*)d_in[2];
    const float* p_vs   = (const float*)d_in[3];
    const float* p_vmax = (const float*)d_in[4];
    const float* p_rc   = (const float*)d_in[5];
    const float* p_Rd   = (const float*)d_in[6];
    const float* p_hz   = (const float*)d_in[7];
    const float* freqs  = (const float*)d_in[8];
    float* out = (float*)d_out;

    dim3 grid(NWAVES / 4);
    dim3 block(256);
    cube_sim_kernel<<<grid, block, 0, stream>>>(p_inc, p_rot, p_lb, p_vs,
                                                p_vmax, p_rc, p_Rd, p_hz,
                                                freqs, out);
}